// Round 17
// baseline (597.509 us; speedup 1.0000x reference)
//
#include <hip/hip_runtime.h>
#include <math.h>

#define TT   256   // timesteps
#define HH   64    // hidden
#define INw  46    // input size
#define NCLS 8     // classes
#define BB   4     // batch rows per scan block (grid 512 = 2 blocks/CU target)
#define CH   4     // timesteps per chunk
#define NCH  (TT / CH)
#define B2   8     // batch rows per epilogue block
#define XS   80    // short stride for x/h LDS rows (160B -> 2-way free aliasing)
#define XCHS 20    // f32 stride per unit in gate-exchange buffer

typedef __attribute__((ext_vector_type(8))) short  short8v;  // 8 bf16
typedef __attribute__((ext_vector_type(4))) float  float4v;

__device__ __forceinline__ float frcp(float x) { return __builtin_amdgcn_rcpf(x); }
__device__ __forceinline__ float sigmoid_f(float x) { return frcp(1.f + __expf(-x)); }
__device__ __forceinline__ float tanh_f(float x) {
    float a = fabsf(x);
    float e = __expf(-2.f * a);
    float r = (1.f - e) * frcp(1.f + e);
    return x >= 0.f ? r : -r;
}
__device__ __forceinline__ float dot4(float4 w, float4 a, float acc) {
    acc = fmaf(w.x, a.x, acc);
    acc = fmaf(w.y, a.y, acc);
    acc = fmaf(w.z, a.z, acc);
    acc = fmaf(w.w, a.w, acc);
    return acc;
}

// float -> bf16 round-to-nearest-even (bit-identical to R10/R14)
__device__ __forceinline__ unsigned short f2bf(float f) {
    unsigned int u = __float_as_uint(f);
    unsigned int r = u + 0x7FFFu + ((u >> 16) & 1u);
    return (unsigned short)(r >> 16);
}
__device__ __forceinline__ float bf2f(unsigned short h) {
    return __uint_as_float(((unsigned int)h) << 16);
}
__device__ __forceinline__ void split8(const float v[8], short8v& hi, short8v& lo) {
#pragma unroll
    for (int e = 0; e < 8; ++e) {
        unsigned short h = f2bf(v[e]);
        hi[e] = (short)h;
        lo[e] = (short)f2bf(v[e] - bf2f(h));
    }
}

#define MFMA16(A,B,C) __builtin_amdgcn_mfma_f32_16x16x32_bf16((A),(B),(C),0,0,0)

// ---------------------------------------------------------------------------
// Gate-split MFMA LSTM scan, 8-wave blocks for 2-block/CU co-residency (R17).
// 512 blocks x 4 batch rows, 512 threads (8 waves = 2/SIMD; two blocks ->
// 4 waves/SIMD, fits the <=128-VGPR bucket -- the co-residency R14's 12-wave
// block could not achieve).
//   waves 0-1 (IF): i,f tiles of 32 units each (ut-loop) -> 24 MFMA;
//                   ph2: cell update + h write (g0 -> hi, g2 -> lo).
//   waves 2-3 (GO): g,o tiles of 32 units -> 24 MFMA + tanh/sig + publish.
//   waves 4-7 (P):  x staging (issue-early/write-late) + zx = x*Wih^T
//                   (verbatim R14 producer: A-tile = 4 timesteps x 4 rows,
//                    one 24-MFMA burst per chunk, zx u^(2t) swizzle).
// h rows alias mod 4. Final h reconstructed from h_hi+h_lo LDS (saves regs).
// Parity: h write = s&1, read = (s+1)&1. 3-term split-bf16, fp32 accumulate.
// ---------------------------------------------------------------------------
__global__ __launch_bounds__(512, 4) void lstm_fwd_mfma(
    const float* __restrict__ x,     // (B,T,46)
    const float* __restrict__ Wih,   // (256,46)
    const float* __restrict__ Whh,   // (256,64)
    const float* __restrict__ bih,   // (256)
    const float* __restrict__ bhh,   // (256)
    float* __restrict__ hf_out)      // (B,64)
{
    __shared__ float zx[2][CH][4][HH][4];    // 32 KB (chunk-parity dbuf)
    __shared__ short x_hi[CH][BB][XS];       // 2.5 KB (single buffer)
    __shared__ short x_lo[CH][BB][XS];       // 2.5 KB
    __shared__ short h_hi[2][BB][XS];        // 1.25 KB (step-parity dbuf)
    __shared__ short h_lo[2][BB][XS];        // 1.25 KB
    __shared__ float xch[HH * XCHS];         // 5 KB gate exchange (g~,o~)

    const int j    = threadIdx.x;
    const int w    = j >> 6;
    const int l    = j & 63;
    const int g    = l >> 4;
    const int c16  = l & 15;
    const int b0   = blockIdx.x * BB;
    const bool isP  = (w >= 4);
    const bool isGO = (w >= 2 && w < 4);
    const bool isIF = (w < 2);
    const int ub = 32 * (w & 1);          // consumer base unit (32 units/wave)
    const int u0 = ub + c16;
    const int u1 = ub + 16 + c16;
    const int up = 16 * (w & 3) + c16;    // producer unit

    // ---- weight fragments (role-dependent contents) ----
    // consumers: wf[2*ut+tq] = Whh hi, wf[4+2*ut+tq] = lo (ut unit-tile, tq gate)
    // producers: wf[q] = Wih hi, wf[4+q] = lo
    short8v wf[8][2];
    float bias4[4] = {0.f, 0.f, 0.f, 0.f};
    if (!isP) {
        const int cb0 = isGO ? 128 : 0;
#pragma unroll
        for (int ut = 0; ut < 2; ++ut) {
#pragma unroll
            for (int tq = 0; tq < 2; ++tq) {
                const int t = 2 * ut + tq;
                const int n = cb0 + 64 * tq + ub + 16 * ut + c16;
                bias4[t] = bih[n] + bhh[n];
#pragma unroll
                for (int s2 = 0; s2 < 2; ++s2) {
                    float vh[8];
#pragma unroll
                    for (int e = 0; e < 8; ++e)
                        vh[e] = Whh[n * HH + 32 * s2 + 8 * g + e];
                    split8(vh, wf[t][s2], wf[4 + t][s2]);
                }
            }
        }
    } else {
#pragma unroll
        for (int q = 0; q < 4; ++q) {
            const int n = 64 * q + up;
#pragma unroll
            for (int s2 = 0; s2 < 2; ++s2) {
                float vi[8];
#pragma unroll
                for (int e = 0; e < 8; ++e) {
                    const int k = 32 * s2 + 8 * g + e;
                    const float tval = Wih[n * INw + ((k < INw) ? k : 0)];
                    vi[e] = (k < INw) ? tval : 0.f;
                }
                split8(vi, wf[q][s2], wf[4 + q][s2]);
            }
        }
    }

    // ================= hoisted addressing =================
    // consumer h fragment bases (rows alias mod 4; +8g k-offset folded)
    const int ro = (c16 & 3) * XS + 8 * g;
    const short* hrh0 = &h_hi[0][0][0] + ro;
    const short* hrh1 = &h_hi[1][0][0] + ro;
    const short* hrl0 = &h_lo[0][0][0] + ro;
    const short* hrl1 = &h_lo[1][0][0] + ro;
    // consumer h write bases: g0 -> hi, g2 -> lo (g1,g3 idle); rows 0..3
    short* hb0 = ((g & 2) ? &h_lo[0][0][0] : &h_hi[0][0][0]);
    short* hb1 = ((g & 2) ? &h_lo[1][0][0] : &h_hi[1][0][0]);
    const int q0 = isGO ? 2 : 0;
    // producer zx write pointers (timestep = g, u swizzled by 2g), per parity
    float* zw0 = &zx[0][g][0][up ^ (2 * g)][0];
    float* zw1 = &zx[1][g][0][up ^ (2 * g)][0];
    // producer x fragment bases (A-row a = c16 -> timestep c16>>2, row c16&3)
    const short* pxh8 = &x_hi[c16 >> 2][c16 & 3][0] + 8 * g;
    const short* pxl8 = &x_lo[c16 >> 2][c16 & 3][0] + 8 * g;
    // staging offsets (P lanes j in [256,512); 736 elems -> 3 slots)
    size_t st_gof[3]; int st_lds[3]; bool st_ok[3];
#pragma unroll
    for (int it = 0; it < 3; ++it) {
        const int e  = (j - 256) + 256 * it;
        const bool ok = (e >= 0) && (e < BB * CH * INw);
        const int ec = ok ? e : 0;
        const int r   = ec / (CH * INw);
        const int rem = ec - r * (CH * INw);
        const int tt  = rem / INw;
        const int k   = rem - tt * INw;
        st_ok[it]  = ok;
        st_gof[it] = ((size_t)(b0 + r) * TT + tt) * INw + k;
        st_lds[it] = (tt * BB + r) * XS + k;
    }
    short* xsh = &x_hi[0][0][0];
    short* xsl = &x_lo[0][0][0];

    // one burst covers the whole next chunk (4 timesteps x 4 rows), 24 MFMA
    auto zx_burst = [&](float* zw) {
        const short8v axh0 = *(const short8v*)(pxh8);
        const short8v axh1 = *(const short8v*)(pxh8 + 32);
        const short8v axl0 = *(const short8v*)(pxl8);
        const short8v axl1 = *(const short8v*)(pxl8 + 32);
#pragma unroll
        for (int q = 0; q < 4; ++q) {
            float4v A1 = {0.f, 0.f, 0.f, 0.f};
            float4v A2 = {0.f, 0.f, 0.f, 0.f};
            float4v A3 = {0.f, 0.f, 0.f, 0.f};
            A1 = MFMA16(axh0, wf[q][0], A1);
            A2 = MFMA16(axh0, wf[4 + q][0], A2);
            A3 = MFMA16(axl0, wf[q][0], A3);
            A1 = MFMA16(axh1, wf[q][1], A1);
            A2 = MFMA16(axh1, wf[4 + q][1], A2);
            A3 = MFMA16(axl1, wf[q][1], A3);
            *(float4v*)(zw + q * 256) = (A1 + A2) + A3;
        }
    };

    // ---- zero LDS (h both parities; x incl. k>=46 pad — staging only
    //      writes k<46 so the pad stays zero for all chunks) ----
    {
        short* p1 = &h_hi[0][0][0]; short* p2 = &h_lo[0][0][0];
        for (int idx = j; idx < 2 * BB * XS; idx += 512) { p1[idx] = 0; p2[idx] = 0; }
        for (int idx = j; idx < CH * BB * XS; idx += 512) { xsh[idx] = 0; xsl[idx] = 0; }
    }
    __syncthreads();

    // ---- stage x chunk 0 (all threads; 736 elements) ----
    for (int e = j; e < BB * CH * INw; e += 512) {
        const int r   = e / (CH * INw);
        const int rem = e - r * (CH * INw);
        const int tt  = rem / INw;
        const int k   = rem - tt * INw;
        const float v = x[((size_t)(b0 + r) * TT + tt) * INw + k];
        const unsigned short hh = f2bf(v);
        x_hi[tt][r][k] = (short)hh;
        x_lo[tt][r][k] = (short)f2bf(v - bf2f(hh));
    }
    __syncthreads();

    // ---- prologue: zx[0] (producers) + issue global loads for chunk 1 ----
    float xhold[3];
    if (isP) {
        zx_burst(zw0);
#pragma unroll
        for (int it = 0; it < 3; ++it)
            if (st_ok[it]) xhold[it] = x[st_gof[it] + (size_t)(CH * INw)];
    }

    float cst0[4] = {0.f, 0.f, 0.f, 0.f};
    float cst1[4] = {0.f, 0.f, 0.f, 0.f};
    __syncthreads();

    for (int c = 0; c < NCH; ++c) {
        const int cb = c & 1;
#pragma unroll
        for (int s = 0; s < CH; ++s) {
            float4v C0a, C1a, C0b, C1b;   // consumer pre-activation (ut0, ut1)
            const float4v z4 = {0.f, 0.f, 0.f, 0.f};
            // ======== PHASE 1: MFMA + activate (consumers) / P work ========
            if (!isP) {
                const int rp = (s + 1) & 1;
                const short* hrh = rp ? hrh1 : hrh0;
                const short* hrl = rp ? hrl1 : hrl0;
                const short8v ahh0 = *(const short8v*)(hrh);
                const short8v ahh1 = *(const short8v*)(hrh + 32);
                const short8v ahl0 = *(const short8v*)(hrl);
                const short8v ahl1 = *(const short8v*)(hrl + 32);
                const float* zr0 = &zx[cb][s][q0][u0 ^ (2 * s)][0];
                const float* zr1 = &zx[cb][s][q0][u1 ^ (2 * s)][0];
                C0a = *(const float4v*)(zr0);
                C1a = *(const float4v*)(zr0 + 256);
                C0b = *(const float4v*)(zr1);
                C1b = *(const float4v*)(zr1 + 256);
                float4v D0, D1;
                __builtin_amdgcn_s_setprio(1);
                // ---- ut = 0 (tiles 0,1) ----
                D0 = z4; D1 = z4;
                C0a = MFMA16(ahh0, wf[0][0], C0a);
                C1a = MFMA16(ahh0, wf[1][0], C1a);
                D0  = MFMA16(ahl0, wf[0][0], D0);
                D1  = MFMA16(ahl0, wf[1][0], D1);
                C0a = MFMA16(ahh1, wf[0][1], C0a);
                C1a = MFMA16(ahh1, wf[1][1], C1a);
                D0  = MFMA16(ahl1, wf[0][1], D0);
                D1  = MFMA16(ahl1, wf[1][1], D1);
                D0  = MFMA16(ahh0, wf[4][0], D0);
                D1  = MFMA16(ahh0, wf[5][0], D1);
                D0  = MFMA16(ahh1, wf[4][1], D0);
                D1  = MFMA16(ahh1, wf[5][1], D1);
                C0a += D0; C1a += D1;
                // ---- ut = 1 (tiles 2,3) ----
                D0 = z4; D1 = z4;
                C0b = MFMA16(ahh0, wf[2][0], C0b);
                C1b = MFMA16(ahh0, wf[3][0], C1b);
                D0  = MFMA16(ahl0, wf[2][0], D0);
                D1  = MFMA16(ahl0, wf[3][0], D1);
                C0b = MFMA16(ahh1, wf[2][1], C0b);
                C1b = MFMA16(ahh1, wf[3][1], C1b);
                D0  = MFMA16(ahl1, wf[2][1], D0);
                D1  = MFMA16(ahl1, wf[3][1], D1);
                D0  = MFMA16(ahh0, wf[6][0], D0);
                D1  = MFMA16(ahh0, wf[7][0], D1);
                D0  = MFMA16(ahh1, wf[6][1], D0);
                D1  = MFMA16(ahh1, wf[7][1], D1);
                C0b += D0; C1b += D1;
                __builtin_amdgcn_s_setprio(0);
                if (isGO) {
                    float gt0[4], ot0[4], gt1[4], ot1[4];
#pragma unroll
                    for (int r = 0; r < 4; ++r) {
                        gt0[r] = tanh_f(C0a[r] + bias4[0]);
                        ot0[r] = sigmoid_f(C1a[r] + bias4[1]);
                        gt1[r] = tanh_f(C0b[r] + bias4[2]);
                        ot1[r] = sigmoid_f(C1b[r] + bias4[3]);
                    }
                    if (g == 0) {
                        float4v A, Bv;
                        A[0] = gt0[0]; A[1] = ot0[0]; A[2] = gt0[1]; A[3] = ot0[1];
                        Bv[0] = gt0[2]; Bv[1] = ot0[2]; Bv[2] = gt0[3]; Bv[3] = ot0[3];
                        *(float4v*)&xch[u0 * XCHS] = A;
                        *(float4v*)(&xch[u0 * XCHS] + 4) = Bv;
                        A[0] = gt1[0]; A[1] = ot1[0]; A[2] = gt1[1]; A[3] = ot1[1];
                        Bv[0] = gt1[2]; Bv[1] = ot1[2]; Bv[2] = gt1[3]; Bv[3] = ot1[3];
                        *(float4v*)&xch[u1 * XCHS] = A;
                        *(float4v*)(&xch[u1 * XCHS] + 4) = Bv;
                    }
                }
            } else {
                if (s == 1 && c + 1 < NCH) {
                    zx_burst((c & 1) ? zw0 : zw1);   // next chunk's parity
                } else if (s == 3 && c + 2 < NCH) {
                    const size_t cofs = (size_t)(c + 2) * (CH * INw);
#pragma unroll
                    for (int it = 0; it < 3; ++it)
                        if (st_ok[it]) xhold[it] = x[st_gof[it] + cofs];
                }
            }
            __syncthreads();   // B1: gate pairs published
            // ======== PHASE 2: update (IF) / staging write (P) =============
            if (isIF) {
                short* dsel = ((s & 1) ? hb1 : hb0);
                // ---- ut0 ----
                {
                    const float* xr = &xch[u0 * XCHS];
                    const float4v A  = *(const float4v*)xr;
                    const float4v Bv = *(const float4v*)(xr + 4);
                    const float gv[4] = {A[0], A[2], Bv[0], Bv[2]};
                    const float ov[4] = {A[1], A[3], Bv[1], Bv[3]};
                    short* dst = dsel + u0;
#pragma unroll
                    for (int r = 0; r < 4; ++r) {
                        const float iv = sigmoid_f(C0a[r] + bias4[0]);
                        const float fv = sigmoid_f(C1a[r] + bias4[1]);
                        cst0[r] = fmaf(fv, cst0[r], iv * gv[r]);
                        const float hn = ov[r] * tanh_f(cst0[r]);
                        if ((g & 1) == 0) {
                            const unsigned short hh = f2bf(hn);
                            dst[r * XS] = (g & 2) ? (short)f2bf(hn - bf2f(hh))
                                                  : (short)hh;
                        }
                    }
                }
                // ---- ut1 ----
                {
                    const float* xr = &xch[u1 * XCHS];
                    const float4v A  = *(const float4v*)xr;
                    const float4v Bv = *(const float4v*)(xr + 4);
                    const float gv[4] = {A[0], A[2], Bv[0], Bv[2]};
                    const float ov[4] = {A[1], A[3], Bv[1], Bv[3]};
                    short* dst = dsel + u1;
#pragma unroll
                    for (int r = 0; r < 4; ++r) {
                        const float iv = sigmoid_f(C0b[r] + bias4[2]);
                        const float fv = sigmoid_f(C1b[r] + bias4[3]);
                        cst1[r] = fmaf(fv, cst1[r], iv * gv[r]);
                        const float hn = ov[r] * tanh_f(cst1[r]);
                        if ((g & 1) == 0) {
                            const unsigned short hh = f2bf(hn);
                            dst[r * XS] = (g & 2) ? (short)f2bf(hn - bf2f(hh))
                                                  : (short)hh;
                        }
                    }
                }
            } else if (isP) {
                if (s == 0 && c + 1 < NCH) {
#pragma unroll
                    for (int it = 0; it < 3; ++it) {
                        if (st_ok[it]) {
                            const unsigned short hh = f2bf(xhold[it]);
                            xsh[st_lds[it]] = (short)hh;
                            xsl[st_lds[it]] = (short)f2bf(xhold[it] - bf2f(hh));
                        }
                    }
                }
            }
            __syncthreads();   // B2: h + x published
        }
    }

    // final h = hi + lo from LDS (last write parity: t=255 -> s&1 = 1)
    if (j < BB * HH) {
        const int r  = j >> 6;
        const int un = j & 63;
        const float hv = bf2f((unsigned short)h_hi[1][r][un])
                       + bf2f((unsigned short)h_lo[1][r][un]);
        hf_out[(size_t)(b0 + r) * HH + un] = hv;
    }
}

// ---------------------------------------------------------------------------
// Epilogue: backward dir = ONE LSTM step on x[:,T-1,:] (h0=c0=0, Whh_b unused),
// then FC + softmax.
// ---------------------------------------------------------------------------
__global__ __launch_bounds__(256) void lstm_bwd_fc(
    const float* __restrict__ x,
    const float* __restrict__ Wih,
    const float* __restrict__ bih,
    const float* __restrict__ bhh,
    const float* __restrict__ fcW,
    const float* __restrict__ fcb,
    const float* __restrict__ hf,
    float* __restrict__ out)
{
    __shared__ float xl[B2][48];
    __shared__ float act[B2][256];
    __shared__ float hbl[B2][HH];

    const int j  = threadIdx.x;
    const int b0 = blockIdx.x * B2;

    for (int e = j; e < B2 * INw; e += 256) {
        int b = e / INw, i = e - b * INw;
        xl[b][i] = x[((size_t)(b0 + b) * TT + (TT - 1)) * INw + i];
    }
    if (j < B2) { xl[j][46] = 0.f; xl[j][47] = 0.f; }
    __syncthreads();

    float4 wih4[12];
#pragma unroll
    for (int ii = 0; ii < 11; ++ii)
        wih4[ii] = make_float4(Wih[j*INw + 4*ii + 0], Wih[j*INw + 4*ii + 1],
                               Wih[j*INw + 4*ii + 2], Wih[j*INw + 4*ii + 3]);
    wih4[11] = make_float4(Wih[j*INw + 44], Wih[j*INw + 45], 0.f, 0.f);
    const float bias = bih[j] + bhh[j];
    const bool  gate_is_tanh = ((j >> 6) == 2);

#pragma unroll
    for (int b = 0; b < B2; ++b) {
        float a = bias;
#pragma unroll
        for (int ii = 0; ii < 12; ++ii) {
            float4 xv = *(const float4*)&xl[b][4*ii];
            a = dot4(wih4[ii], xv, a);
        }
        act[b][j] = gate_is_tanh ? tanh_f(a) : sigmoid_f(a);
    }
    __syncthreads();

    for (int q = j; q < B2 * HH; q += 256) {
        int b = q >> 6, ll = q & 63;
        float ig = act[b][ll];
        float gg = act[b][128 + ll];
        float og = act[b][192 + ll];
        hbl[b][ll] = og * tanh_f(ig * gg);
    }
    __syncthreads();

    if (j < B2 * NCLS) {
        int b = j >> 3, n = j & 7;
        float a = fcb[n];
        const float* hfr = hf + (size_t)(b0 + b) * HH;
#pragma unroll
        for (int ll = 0; ll < HH; ++ll) {
            a = fmaf(fcW[n * 2 * HH + ll],      hfr[ll],    a);
            a = fmaf(fcW[n * 2 * HH + HH + ll], hbl[b][ll], a);
        }
        float m = a;
        m = fmaxf(m, __shfl_xor(m, 1, 8));
        m = fmaxf(m, __shfl_xor(m, 2, 8));
        m = fmaxf(m, __shfl_xor(m, 4, 8));
        float e = __expf(a - m);
        float s = e;
        s += __shfl_xor(s, 1, 8);
        s += __shfl_xor(s, 2, 8);
        s += __shfl_xor(s, 4, 8);
        out[(size_t)(b0 + b) * NCLS + n] = e / s;
    }
}

extern "C" void kernel_launch(void* const* d_in, const int* in_sizes, int n_in,
                              void* d_out, int out_size, void* d_ws, size_t ws_size,
                              hipStream_t stream) {
    const float* x     = (const float*)d_in[0];
    const float* Wih_f = (const float*)d_in[1];
    const float* Whh_f = (const float*)d_in[2];
    const float* bih_f = (const float*)d_in[3];
    const float* bhh_f = (const float*)d_in[4];
    const float* Wih_b = (const float*)d_in[5];
    // d_in[6] = Whh_b: unused — backward dir contributes only its first step (h0=0)
    const float* bih_b = (const float*)d_in[7];
    const float* bhh_b = (const float*)d_in[8];
    const float* fcW   = (const float*)d_in[9];
    const float* fcb   = (const float*)d_in[10];
    float* out = (float*)d_out;
    float* hf  = (float*)d_ws;   // 2048*64 fp32 = 512 KB scratch

    hipLaunchKernelGGL(lstm_fwd_mfma, dim3(2048 / BB), dim3(512), 0, stream,
                       x, Wih_f, Whh_f, bih_f, bhh_f, hf);
    hipLaunchKernelGGL(lstm_bwd_fc, dim3(2048 / B2), dim3(256), 0, stream,
                       x, Wih_b, bih_b, bhh_b, fcW, fcb, hf, out);
}

// Round 18
// 252.743 us; speedup vs baseline: 2.3641x; 2.3641x over previous
//
#include <hip/hip_runtime.h>
#include <math.h>

#define TT   256   // timesteps
#define HH   64    // hidden
#define INw  46    // input size
#define NCLS 8     // classes
#define BB   8     // batch rows per scan block (grid 256)
#define CH   4     // timesteps per chunk
#define NCH  (TT / CH)
#define B2   8     // batch rows per epilogue block
#define XS   80    // short stride for x/h LDS rows (160B -> 2-way free aliasing)
#define XCHS 20    // f32 stride per unit in gate-exchange buffer

typedef __attribute__((ext_vector_type(8))) short  short8v;  // 8 bf16
typedef __attribute__((ext_vector_type(4))) float  float4v;

__device__ __forceinline__ float frcp(float x) { return __builtin_amdgcn_rcpf(x); }
__device__ __forceinline__ float sigmoid_f(float x) { return frcp(1.f + __expf(-x)); }
__device__ __forceinline__ float tanh_f(float x) {
    float a = fabsf(x);
    float e = __expf(-2.f * a);
    float r = (1.f - e) * frcp(1.f + e);
    return x >= 0.f ? r : -r;
}
__device__ __forceinline__ float dot4(float4 w, float4 a, float acc) {
    acc = fmaf(w.x, a.x, acc);
    acc = fmaf(w.y, a.y, acc);
    acc = fmaf(w.z, a.z, acc);
    acc = fmaf(w.w, a.w, acc);
    return acc;
}

// float -> bf16 round-to-nearest-even
__device__ __forceinline__ unsigned short f2bf(float f) {
    unsigned int u = __float_as_uint(f);
    unsigned int r = u + 0x7FFFu + ((u >> 16) & 1u);
    return (unsigned short)(r >> 16);
}
__device__ __forceinline__ float bf2f(unsigned short h) {
    return __uint_as_float(((unsigned int)h) << 16);
}
__device__ __forceinline__ void split8(const float v[8], short8v& hi, short8v& lo) {
#pragma unroll
    for (int e = 0; e < 8; ++e) {
        unsigned short h = f2bf(v[e]);
        hi[e] = (short)h;
        lo[e] = (short)f2bf(v[e] - bf2f(h));
    }
}

#define MFMA16(A,B,C) __builtin_amdgcn_mfma_f32_16x16x32_bf16((A),(B),(C),0,0,0)

// ---------------------------------------------------------------------------
// Gate-split MFMA LSTM scan, 16-wave block = 4 waves/SIMD in ONE block (R18).
// R16/R10 structure verbatim for consumers; producer role split into two
// 4-wave groups each owning 2 gates (halves producer weight registers so the
// forced 128 combined VGPR+AGPR cap is met WITHOUT spill — R17's failure).
//   waves 0-3  (IF): i,f tiles -> 12 MFMA; ph2: cell update + h write.
//   waves 4-7  (GO): g,o tiles -> 12 MFMA + tanh/sig + exchange write.
//   waves 8-11 (P0): staging + zx gates {0,1} (12 MFMA/burst).
//   waves 12-15(P1): staging + zx gates {2,3} (12 MFMA/burst).
// Numerics: 3-term split-bf16 products, fp32 accumulate — bit-identical to
// R16 (only the wave computing each zx gate-pair changes; regions disjoint).
// 2 barriers/step. All 16 waves resident by definition -> 50% occupancy.
// ---------------------------------------------------------------------------
__global__ __launch_bounds__(1024, 1) void lstm_fwd_mfma(
    const float* __restrict__ x,     // (B,T,46)
    const float* __restrict__ Wih,   // (256,46)
    const float* __restrict__ Whh,   // (256,64)
    const float* __restrict__ bih,   // (256)
    const float* __restrict__ bhh,   // (256)
    float* __restrict__ hf_out)      // (B,64)
{
    __shared__ float zx[2][CH][4][HH][8];    // 64 KB (chunk-parity dbuf)
    __shared__ short x_hi[CH][BB][XS];       // 5 KB  (single buffer)
    __shared__ short x_lo[CH][BB][XS];       // 5 KB
    __shared__ short h_hi[2][BB][XS];        // 2.5 KB (step-parity dbuf)
    __shared__ short h_lo[2][BB][XS];        // 2.5 KB
    __shared__ float xch[HH * XCHS];         // 5 KB gate exchange (g~,o~)

    const int j    = threadIdx.x;
    const int w    = j >> 6;
    const int l    = j & 63;
    const int g    = l >> 4;
    const int c16  = l & 15;
    const int b0   = blockIdx.x * BB;
    const int wl   = w & 3;
    const int u    = 16 * wl + c16;
    const int r0p  = ((g & 1) * 4) ^ (u & 4);
    const bool isP  = (w >= 8);
    const bool isGO = (w >= 4 && w < 8);
    const bool isIF = (w < 4);
    const int  pg   = (w >= 12) ? 1 : 0;     // producer gate-pair group

    // ---- weight fragments (role-dependent contents) ----
    // consumers: wf[tq]=Whh_hi, wf[2+tq]=Whh_lo (tq = gate tile 0,1)
    // producers: wf[qq]=Wih_hi, wf[2+qq]=Wih_lo for gates q = 2*pg+qq
    short8v wf[4][2];
    float bias2[2] = {0.f, 0.f};
    if (!isP) {
        const int cb0 = isGO ? 128 : 0;
#pragma unroll
        for (int tq = 0; tq < 2; ++tq) {
            const int n = cb0 + 64 * tq + u;
            bias2[tq] = bih[n] + bhh[n];
#pragma unroll
            for (int s2 = 0; s2 < 2; ++s2) {
                float vh[8];
#pragma unroll
                for (int e = 0; e < 8; ++e)
                    vh[e] = Whh[n * HH + 32 * s2 + 8 * g + e];
                split8(vh, wf[tq][s2], wf[2 + tq][s2]);
            }
        }
    } else {
#pragma unroll
        for (int qq = 0; qq < 2; ++qq) {
            const int n = 64 * (2 * pg + qq) + u;
#pragma unroll
            for (int s2 = 0; s2 < 2; ++s2) {
                float vi[8];
#pragma unroll
                for (int e = 0; e < 8; ++e) {
                    const int k = 32 * s2 + 8 * g + e;
                    const float tval = Wih[n * INw + ((k < INw) ? k : 0)];
                    vi[e] = (k < INw) ? tval : 0.f;
                }
                split8(vi, wf[qq][s2], wf[2 + qq][s2]);
            }
        }
    }

    // ---- zero h bufs and x bufs (incl. k>=46 pad; staging writes only k<46,
    //      pad stays zero across all chunks) ----
    {
        short* hh0 = &h_hi[0][0][0];
        short* hl0 = &h_lo[0][0][0];
        for (int idx = j; idx < 2 * BB * XS; idx += 1024) {
            hh0[idx] = 0;
            hl0[idx] = 0;
        }
        short* xh0 = &x_hi[0][0][0];
        short* xl0 = &x_lo[0][0][0];
        for (int idx = j; idx < CH * BB * XS; idx += 1024) {
            xh0[idx] = 0;
            xl0[idx] = 0;
        }
    }
    __syncthreads();

    // ---- stage x chunk 0 (all threads) ----
    for (int e = j; e < BB * CH * INw; e += 1024) {
        const int r   = e / (CH * INw);
        const int rem = e - r * (CH * INw);
        const int tt  = rem / INw;
        const int k   = rem - tt * INw;
        const float v = x[((size_t)(b0 + r) * TT + tt) * INw + k];
        const unsigned short hh = f2bf(v);
        x_hi[tt][r][k] = (short)hh;
        x_lo[tt][r][k] = (short)f2bf(v - bf2f(hh));
    }
    __syncthreads();

    // zx producer burst: this group's 2 gates (q = 2*pg + qq)
    auto zx_burst = [&](int tau, int nbuf) {
        const int trel = 2 * tau + (c16 >> 3);
        const int rr   = c16 & 7;
        const short* ph = &x_hi[trel][rr][0] + 8 * g;
        const short* pl = &x_lo[trel][rr][0] + 8 * g;
        const short8v axh0 = *(const short8v*)(ph);
        const short8v axh1 = *(const short8v*)(ph + 32);
        const short8v axl0 = *(const short8v*)(pl);
        const short8v axl1 = *(const short8v*)(pl + 32);
        const int tout = 2 * tau + (g >> 1);
#pragma unroll
        for (int qq = 0; qq < 2; ++qq) {
            const int q = 2 * pg + qq;
            float4v C = {0.f, 0.f, 0.f, 0.f};
            C = MFMA16(axh0, wf[qq][0], C);
            C = MFMA16(axh1, wf[qq][1], C);
            C = MFMA16(axh0, wf[2 + qq][0], C);
            C = MFMA16(axh1, wf[2 + qq][1], C);
            C = MFMA16(axl0, wf[qq][0], C);
            C = MFMA16(axl1, wf[qq][1], C);
            *(float4v*)&zx[nbuf][tout][q][u][r0p] = C;
        }
    };

    // staging offsets (P lanes: j-512 in [0,512); 1472 elems -> 3 slots)
    size_t st_gof[3]; int st_lds[3]; bool st_ok[3];
#pragma unroll
    for (int it = 0; it < 3; ++it) {
        const int e  = (j - 512) + 512 * it;
        const bool ok = (e >= 0) && (e < BB * CH * INw);
        const int ec = ok ? e : 0;
        const int r   = ec / (CH * INw);
        const int rem = ec - r * (CH * INw);
        const int tt  = rem / INw;
        const int k   = rem - tt * INw;
        st_ok[it]  = ok;
        st_gof[it] = ((size_t)(b0 + r) * TT + tt) * INw + k;
        st_lds[it] = (tt * BB + r) * XS + k;
    }
    short* xsh = &x_hi[0][0][0];
    short* xsl = &x_lo[0][0][0];

    // ---- prologue: zx[0] (producers) + issue global loads for chunk 1 ----
    float xhold[3];
    if (isP) {
        zx_burst(0, 0);
        zx_burst(1, 0);
#pragma unroll
        for (int it = 0; it < 3; ++it)
            if (st_ok[it]) xhold[it] = x[st_gof[it] + (size_t)(CH * INw)];
    }

    float cst[4]  = {0.f, 0.f, 0.f, 0.f};
    float hnew[4] = {0.f, 0.f, 0.f, 0.f};
    __syncthreads();

    for (int c = 0; c < NCH; ++c) {
        const int cb = c & 1, nb = cb ^ 1;
#pragma unroll
        for (int s = 0; s < CH; ++s) {
            const int t = c * CH + s;
            float4v C0, C1;
            // ======== PHASE 1: MFMA (consumers) / zx + load-issue (P) ======
            if (!isP) {
                const short* hrh = &h_hi[(t + 1) & 1][0][0];
                const short* hrl = &h_lo[(t + 1) & 1][0][0];
                const int ro = (c16 & 7) * XS;
                const short8v ahh0 = *(const short8v*)(hrh + ro + 8 * g);
                const short8v ahh1 = *(const short8v*)(hrh + ro + 32 + 8 * g);
                const short8v ahl0 = *(const short8v*)(hrl + ro + 8 * g);
                const short8v ahl1 = *(const short8v*)(hrl + ro + 32 + 8 * g);
                const int q0 = isGO ? 2 : 0;
                C0 = *(const float4v*)&zx[cb][s][q0][u][r0p];
                C1 = *(const float4v*)&zx[cb][s][q0 + 1][u][r0p];
                float4v D0 = {0.f, 0.f, 0.f, 0.f};
                float4v D1 = {0.f, 0.f, 0.f, 0.f};
                __builtin_amdgcn_s_setprio(1);
                C0 = MFMA16(ahh0, wf[0][0], C0);
                C1 = MFMA16(ahh0, wf[1][0], C1);
                D0 = MFMA16(ahl0, wf[0][0], D0);
                D1 = MFMA16(ahl0, wf[1][0], D1);
                C0 = MFMA16(ahh1, wf[0][1], C0);
                C1 = MFMA16(ahh1, wf[1][1], C1);
                D0 = MFMA16(ahl1, wf[0][1], D0);
                D1 = MFMA16(ahl1, wf[1][1], D1);
                D0 = MFMA16(ahh0, wf[2][0], D0);
                D1 = MFMA16(ahh0, wf[3][0], D1);
                D0 = MFMA16(ahh1, wf[2][1], D0);
                D1 = MFMA16(ahh1, wf[3][1], D1);
                __builtin_amdgcn_s_setprio(0);
                C0 += D0;
                C1 += D1;
                if (isGO) {
                    float gt[4], ot[4];
#pragma unroll
                    for (int r = 0; r < 4; ++r) {
                        gt[r] = tanh_f(C0[r] + bias2[0]);
                        ot[r] = sigmoid_f(C1[r] + bias2[1]);
                    }
                    if (g < 2) {
                        float4v A, Bv;
                        A[0] = gt[0]; A[1] = ot[0]; A[2] = gt[1]; A[3] = ot[1];
                        Bv[0] = gt[2]; Bv[1] = ot[2]; Bv[2] = gt[3]; Bv[3] = ot[3];
                        float* p = &xch[u * XCHS + 8 * g];
                        *(float4v*)p = A;
                        *(float4v*)(p + 4) = Bv;
                    }
                }
            } else {
                if (s == 1 && c + 1 < NCH) {
                    zx_burst(0, nb);
                } else if (s == 3 && c + 2 < NCH) {
                    const size_t cofs = (size_t)(c + 2) * (CH * INw);
#pragma unroll
                    for (int it = 0; it < 3; ++it)
                        if (st_ok[it]) xhold[it] = x[st_gof[it] + cofs];
                }
            }
            __syncthreads();   // B1: exchange published
            // ======== PHASE 2: update (IF) / staging write + zx (P) ========
            if (isIF) {
                const float* xrd = &xch[u * XCHS + 8 * (g & 1)];
                const float4v A  = *(const float4v*)xrd;
                const float4v Bv = *(const float4v*)(xrd + 4);
                const float gv[4] = {A[0], A[2], Bv[0], Bv[2]};
                const float ov[4] = {A[1], A[3], Bv[1], Bv[3]};
#pragma unroll
                for (int r = 0; r < 4; ++r) {
                    const float iv = sigmoid_f(C0[r] + bias2[0]);
                    const float fv = sigmoid_f(C1[r] + bias2[1]);
                    cst[r]  = fmaf(fv, cst[r], iv * gv[r]);
                    hnew[r] = ov[r] * tanh_f(cst[r]);
                }
                short* hwh = &h_hi[t & 1][0][0];
                short* hwl = &h_lo[t & 1][0][0];
                short* dst = ((g & 2) ? hwl : hwh) + 4 * (g & 1) * XS + u;
                const bool lo = (g & 2) != 0;
#pragma unroll
                for (int r = 0; r < 4; ++r) {
                    const unsigned short hh = f2bf(hnew[r]);
                    const short val = lo ? (short)f2bf(hnew[r] - bf2f(hh)) : (short)hh;
                    dst[r * XS] = val;
                }
            } else if (isP) {
                if (s == 0 && c + 1 < NCH) {
#pragma unroll
                    for (int it = 0; it < 3; ++it) {
                        if (st_ok[it]) {
                            const unsigned short hh = f2bf(xhold[it]);
                            xsh[st_lds[it]] = (short)hh;
                            xsl[st_lds[it]] = (short)f2bf(xhold[it] - bf2f(hh));
                        }
                    }
                } else if (s == 2 && c + 1 < NCH) {
                    zx_burst(1, nb);
                }
            }
            __syncthreads();   // B2: h + x published
        }
    }

    if (isIF && g < 2) {
#pragma unroll
        for (int r = 0; r < 4; ++r)
            hf_out[(size_t)(b0 + 4 * g + r) * HH + u] = hnew[r];
    }
}

// ---------------------------------------------------------------------------
// Epilogue: backward dir = ONE LSTM step on x[:,T-1,:] (h0=c0=0, Whh_b unused),
// then FC + softmax.
// ---------------------------------------------------------------------------
__global__ __launch_bounds__(256) void lstm_bwd_fc(
    const float* __restrict__ x,
    const float* __restrict__ Wih,
    const float* __restrict__ bih,
    const float* __restrict__ bhh,
    const float* __restrict__ fcW,
    const float* __restrict__ fcb,
    const float* __restrict__ hf,
    float* __restrict__ out)
{
    __shared__ float xl[B2][48];
    __shared__ float act[B2][256];
    __shared__ float hbl[B2][HH];

    const int j  = threadIdx.x;
    const int b0 = blockIdx.x * B2;

    for (int e = j; e < B2 * INw; e += 256) {
        int b = e / INw, i = e - b * INw;
        xl[b][i] = x[((size_t)(b0 + b) * TT + (TT - 1)) * INw + i];
    }
    if (j < B2) { xl[j][46] = 0.f; xl[j][47] = 0.f; }
    __syncthreads();

    float4 wih4[12];
#pragma unroll
    for (int ii = 0; ii < 11; ++ii)
        wih4[ii] = make_float4(Wih[j*INw + 4*ii + 0], Wih[j*INw + 4*ii + 1],
                               Wih[j*INw + 4*ii + 2], Wih[j*INw + 4*ii + 3]);
    wih4[11] = make_float4(Wih[j*INw + 44], Wih[j*INw + 45], 0.f, 0.f);
    const float bias = bih[j] + bhh[j];
    const bool  gate_is_tanh = ((j >> 6) == 2);

#pragma unroll
    for (int b = 0; b < B2; ++b) {
        float a = bias;
#pragma unroll
        for (int ii = 0; ii < 12; ++ii) {
            float4 xv = *(const float4*)&xl[b][4*ii];
            a = dot4(wih4[ii], xv, a);
        }
        act[b][j] = gate_is_tanh ? tanh_f(a) : sigmoid_f(a);
    }
    __syncthreads();

    for (int q = j; q < B2 * HH; q += 256) {
        int b = q >> 6, ll = q & 63;
        float ig = act[b][ll];
        float gg = act[b][128 + ll];
        float og = act[b][192 + ll];
        hbl[b][ll] = og * tanh_f(ig * gg);
    }
    __syncthreads();

    if (j < B2 * NCLS) {
        int b = j >> 3, n = j & 7;
        float a = fcb[n];
        const float* hfr = hf + (size_t)(b0 + b) * HH;
#pragma unroll
        for (int ll = 0; ll < HH; ++ll) {
            a = fmaf(fcW[n * 2 * HH + ll],      hfr[ll],    a);
            a = fmaf(fcW[n * 2 * HH + HH + ll], hbl[b][ll], a);
        }
        float m = a;
        m = fmaxf(m, __shfl_xor(m, 1, 8));
        m = fmaxf(m, __shfl_xor(m, 2, 8));
        m = fmaxf(m, __shfl_xor(m, 4, 8));
        float e = __expf(a - m);
        float s = e;
        s += __shfl_xor(s, 1, 8);
        s += __shfl_xor(s, 2, 8);
        s += __shfl_xor(s, 4, 8);
        out[(size_t)(b0 + b) * NCLS + n] = e / s;
    }
}

extern "C" void kernel_launch(void* const* d_in, const int* in_sizes, int n_in,
                              void* d_out, int out_size, void* d_ws, size_t ws_size,
                              hipStream_t stream) {
    const float* x     = (const float*)d_in[0];
    const float* Wih_f = (const float*)d_in[1];
    const float* Whh_f = (const float*)d_in[2];
    const float* bih_f = (const float*)d_in[3];
    const float* bhh_f = (const float*)d_in[4];
    const float* Wih_b = (const float*)d_in[5];
    // d_in[6] = Whh_b: unused — backward dir contributes only its first step (h0=0)
    const float* bih_b = (const float*)d_in[7];
    const float* bhh_b = (const float*)d_in[8];
    const float* fcW   = (const float*)d_in[9];
    const float* fcb   = (const float*)d_in[10];
    float* out = (float*)d_out;
    float* hf  = (float*)d_ws;   // 2048*64 fp32 = 512 KB scratch

    hipLaunchKernelGGL(lstm_fwd_mfma, dim3(2048 / BB), dim3(1024), 0, stream,
                       x, Wih_f, Whh_f, bih_f, bhh_f, hf);
    hipLaunchKernelGGL(lstm_bwd_fc, dim3(2048 / B2), dim3(256), 0, stream,
                       x, Wih_b, bih_b, bhh_b, fcW, fcb, hf, out);
}

// Round 19
// 202.377 us; speedup vs baseline: 2.9524x; 1.2489x over previous
//
#include <hip/hip_runtime.h>
#include <math.h>

#define TT   256   // timesteps
#define HH   64    // hidden
#define INw  46    // input size
#define NCLS 8     // classes
#define BB   8     // batch rows per scan block (grid 256)
#define CH   4     // timesteps per chunk
#define NCH  (TT / CH)
#define B2   8     // batch rows per epilogue block
#define XS   80    // short stride for x/h LDS rows (160B -> 2-way free aliasing)
#define XCHS 20    // f32 stride per unit in gate-exchange buffer

typedef __attribute__((ext_vector_type(8))) short  short8v;  // 8 bf16
typedef __attribute__((ext_vector_type(4))) float  float4v;

__device__ __forceinline__ float frcp(float x) { return __builtin_amdgcn_rcpf(x); }
__device__ __forceinline__ float sigmoid_f(float x) { return frcp(1.f + __expf(-x)); }
__device__ __forceinline__ float tanh_f(float x) {
    float a = fabsf(x);
    float e = __expf(-2.f * a);
    float r = (1.f - e) * frcp(1.f + e);
    return x >= 0.f ? r : -r;
}
__device__ __forceinline__ float dot4(float4 w, float4 a, float acc) {
    acc = fmaf(w.x, a.x, acc);
    acc = fmaf(w.y, a.y, acc);
    acc = fmaf(w.z, a.z, acc);
    acc = fmaf(w.w, a.w, acc);
    return acc;
}

// float -> bf16 round-to-nearest-even
__device__ __forceinline__ unsigned short f2bf(float f) {
    unsigned int u = __float_as_uint(f);
    unsigned int r = u + 0x7FFFu + ((u >> 16) & 1u);
    return (unsigned short)(r >> 16);
}
__device__ __forceinline__ float bf2f(unsigned short h) {
    return __uint_as_float(((unsigned int)h) << 16);
}
__device__ __forceinline__ void split8(const float v[8], short8v& hi, short8v& lo) {
#pragma unroll
    for (int e = 0; e < 8; ++e) {
        unsigned short h = f2bf(v[e]);
        hi[e] = (short)h;
        lo[e] = (short)f2bf(v[e] - bf2f(h));
    }
}

#define MFMA16(A,B,C) __builtin_amdgcn_mfma_f32_16x16x32_bf16((A),(B),(C),0,0,0)

// ---------------------------------------------------------------------------
// Gate-split MFMA LSTM scan, 16-wave block + aliased-lane work-split (R19).
// R18 base; the lane-redundancy (D-rows alias mod 8: g0/g2 hold identical
// batch rows 0-3, g1/g3 rows 4-7) now SPLITS the activation/update work:
// each g-group owns 2 batch rows (g0->0,1  g2->2,3  g1->4,5  g3->6,7).
//   GO: 4 transcendentals/lane (was 8 on half the lanes) -> float4 publish.
//   IF ph2: 4 sigmoid + 2 tanh per lane (was 8+4); writes hi AND lo for its
//   2 rows. Same fp32 ops on same values — only the computing lane changes.
//   waves 8-11 (P0): staging + zx gates {0,1}; waves 12-15 (P1): gates {2,3}.
// 2 barriers/step. 3-term split-bf16, fp32 accumulate (bit-identical).
// ---------------------------------------------------------------------------
__global__ __launch_bounds__(1024, 1) void lstm_fwd_mfma(
    const float* __restrict__ x,     // (B,T,46)
    const float* __restrict__ Wih,   // (256,46)
    const float* __restrict__ Whh,   // (256,64)
    const float* __restrict__ bih,   // (256)
    const float* __restrict__ bhh,   // (256)
    float* __restrict__ hf_out)      // (B,64)
{
    __shared__ float zx[2][CH][4][HH][8];    // 64 KB (chunk-parity dbuf)
    __shared__ short x_hi[CH][BB][XS];       // 5 KB  (single buffer)
    __shared__ short x_lo[CH][BB][XS];       // 5 KB
    __shared__ short h_hi[2][BB][XS];        // 2.5 KB (step-parity dbuf)
    __shared__ short h_lo[2][BB][XS];        // 2.5 KB
    __shared__ float xch[HH * XCHS];         // 5 KB gate exchange (g~,o~)

    const int j    = threadIdx.x;
    const int w    = j >> 6;
    const int l    = j & 63;
    const int g    = l >> 4;
    const int c16  = l & 15;
    const int b0   = blockIdx.x * BB;
    const int wl   = w & 3;
    const int u    = 16 * wl + c16;
    const int r0p  = ((g & 1) * 4) ^ (u & 4);
    const bool isP  = (w >= 8);
    const bool isGO = (w >= 4 && w < 8);
    const bool isIF = (w < 4);
    const int  pg   = (w >= 12) ? 1 : 0;     // producer gate-pair group
    // aliased-lane split: this lane's 2 batch rows and the matching C-reg pair
    const bool hi2  = (g & 2) != 0;          // use C[2],C[3] instead of C[0],C[1]
    const int  row0 = 4 * (g & 1) + 2 * (g >> 1);   // first owned batch row
    const int  xofs = 8 * (g & 1) + 4 * (g >> 1);   // xch offset for my 2 rows

    // ---- weight fragments (role-dependent contents) ----
    short8v wf[4][2];
    float bias2[2] = {0.f, 0.f};
    if (!isP) {
        const int cb0 = isGO ? 128 : 0;
#pragma unroll
        for (int tq = 0; tq < 2; ++tq) {
            const int n = cb0 + 64 * tq + u;
            bias2[tq] = bih[n] + bhh[n];
#pragma unroll
            for (int s2 = 0; s2 < 2; ++s2) {
                float vh[8];
#pragma unroll
                for (int e = 0; e < 8; ++e)
                    vh[e] = Whh[n * HH + 32 * s2 + 8 * g + e];
                split8(vh, wf[tq][s2], wf[2 + tq][s2]);
            }
        }
    } else {
#pragma unroll
        for (int qq = 0; qq < 2; ++qq) {
            const int n = 64 * (2 * pg + qq) + u;
#pragma unroll
            for (int s2 = 0; s2 < 2; ++s2) {
                float vi[8];
#pragma unroll
                for (int e = 0; e < 8; ++e) {
                    const int k = 32 * s2 + 8 * g + e;
                    const float tval = Wih[n * INw + ((k < INw) ? k : 0)];
                    vi[e] = (k < INw) ? tval : 0.f;
                }
                split8(vi, wf[qq][s2], wf[2 + qq][s2]);
            }
        }
    }

    // ---- zero h bufs and x bufs (incl. k>=46 pad; staging writes only k<46,
    //      pad stays zero across all chunks) ----
    {
        short* hh0 = &h_hi[0][0][0];
        short* hl0 = &h_lo[0][0][0];
        for (int idx = j; idx < 2 * BB * XS; idx += 1024) {
            hh0[idx] = 0;
            hl0[idx] = 0;
        }
        short* xh0 = &x_hi[0][0][0];
        short* xl0 = &x_lo[0][0][0];
        for (int idx = j; idx < CH * BB * XS; idx += 1024) {
            xh0[idx] = 0;
            xl0[idx] = 0;
        }
    }
    __syncthreads();

    // ---- stage x chunk 0 (all threads) ----
    for (int e = j; e < BB * CH * INw; e += 1024) {
        const int r   = e / (CH * INw);
        const int rem = e - r * (CH * INw);
        const int tt  = rem / INw;
        const int k   = rem - tt * INw;
        const float v = x[((size_t)(b0 + r) * TT + tt) * INw + k];
        const unsigned short hh = f2bf(v);
        x_hi[tt][r][k] = (short)hh;
        x_lo[tt][r][k] = (short)f2bf(v - bf2f(hh));
    }
    __syncthreads();

    // zx producer burst: this group's 2 gates (q = 2*pg + qq)
    auto zx_burst = [&](int tau, int nbuf) {
        const int trel = 2 * tau + (c16 >> 3);
        const int rr   = c16 & 7;
        const short* ph = &x_hi[trel][rr][0] + 8 * g;
        const short* pl = &x_lo[trel][rr][0] + 8 * g;
        const short8v axh0 = *(const short8v*)(ph);
        const short8v axh1 = *(const short8v*)(ph + 32);
        const short8v axl0 = *(const short8v*)(pl);
        const short8v axl1 = *(const short8v*)(pl + 32);
        const int tout = 2 * tau + (g >> 1);
#pragma unroll
        for (int qq = 0; qq < 2; ++qq) {
            const int q = 2 * pg + qq;
            float4v C = {0.f, 0.f, 0.f, 0.f};
            C = MFMA16(axh0, wf[qq][0], C);
            C = MFMA16(axh1, wf[qq][1], C);
            C = MFMA16(axh0, wf[2 + qq][0], C);
            C = MFMA16(axh1, wf[2 + qq][1], C);
            C = MFMA16(axl0, wf[qq][0], C);
            C = MFMA16(axl1, wf[qq][1], C);
            *(float4v*)&zx[nbuf][tout][q][u][r0p] = C;
        }
    };

    // staging offsets (P lanes: j-512 in [0,512); 1472 elems -> 3 slots)
    size_t st_gof[3]; int st_lds[3]; bool st_ok[3];
#pragma unroll
    for (int it = 0; it < 3; ++it) {
        const int e  = (j - 512) + 512 * it;
        const bool ok = (e >= 0) && (e < BB * CH * INw);
        const int ec = ok ? e : 0;
        const int r   = ec / (CH * INw);
        const int rem = ec - r * (CH * INw);
        const int tt  = rem / INw;
        const int k   = rem - tt * INw;
        st_ok[it]  = ok;
        st_gof[it] = ((size_t)(b0 + r) * TT + tt) * INw + k;
        st_lds[it] = (tt * BB + r) * XS + k;
    }
    short* xsh = &x_hi[0][0][0];
    short* xsl = &x_lo[0][0][0];

    // ---- prologue: zx[0] (producers) + issue global loads for chunk 1 ----
    float xhold[3];
    if (isP) {
        zx_burst(0, 0);
        zx_burst(1, 0);
#pragma unroll
        for (int it = 0; it < 3; ++it)
            if (st_ok[it]) xhold[it] = x[st_gof[it] + (size_t)(CH * INw)];
    }

    float cst2[2]  = {0.f, 0.f};   // cell state for this lane's 2 rows
    float hnew2[2] = {0.f, 0.f};
    __syncthreads();

    for (int c = 0; c < NCH; ++c) {
        const int cb = c & 1, nb = cb ^ 1;
#pragma unroll
        for (int s = 0; s < CH; ++s) {
            const int t = c * CH + s;
            float4v C0, C1;
            // ======== PHASE 1: MFMA (consumers) / zx + load-issue (P) ======
            if (!isP) {
                const short* hrh = &h_hi[(t + 1) & 1][0][0];
                const short* hrl = &h_lo[(t + 1) & 1][0][0];
                const int ro = (c16 & 7) * XS;
                const short8v ahh0 = *(const short8v*)(hrh + ro + 8 * g);
                const short8v ahh1 = *(const short8v*)(hrh + ro + 32 + 8 * g);
                const short8v ahl0 = *(const short8v*)(hrl + ro + 8 * g);
                const short8v ahl1 = *(const short8v*)(hrl + ro + 32 + 8 * g);
                const int q0 = isGO ? 2 : 0;
                C0 = *(const float4v*)&zx[cb][s][q0][u][r0p];
                C1 = *(const float4v*)&zx[cb][s][q0 + 1][u][r0p];
                float4v D0 = {0.f, 0.f, 0.f, 0.f};
                float4v D1 = {0.f, 0.f, 0.f, 0.f};
                __builtin_amdgcn_s_setprio(1);
                C0 = MFMA16(ahh0, wf[0][0], C0);
                C1 = MFMA16(ahh0, wf[1][0], C1);
                D0 = MFMA16(ahl0, wf[0][0], D0);
                D1 = MFMA16(ahl0, wf[1][0], D1);
                C0 = MFMA16(ahh1, wf[0][1], C0);
                C1 = MFMA16(ahh1, wf[1][1], C1);
                D0 = MFMA16(ahl1, wf[0][1], D0);
                D1 = MFMA16(ahl1, wf[1][1], D1);
                D0 = MFMA16(ahh0, wf[2][0], D0);
                D1 = MFMA16(ahh0, wf[3][0], D1);
                D0 = MFMA16(ahh1, wf[2][1], D0);
                D1 = MFMA16(ahh1, wf[3][1], D1);
                __builtin_amdgcn_s_setprio(0);
                C0 += D0;
                C1 += D1;
                if (isGO) {
                    // aliased-lane split: activate only MY 2 rows, publish 4
                    const float p0 = hi2 ? C0[2] : C0[0];
                    const float q0v = hi2 ? C1[2] : C1[0];
                    const float p1 = hi2 ? C0[3] : C0[1];
                    const float q1v = hi2 ? C1[3] : C1[1];
                    float4v A;
                    A[0] = tanh_f(p0 + bias2[0]);
                    A[1] = sigmoid_f(q0v + bias2[1]);
                    A[2] = tanh_f(p1 + bias2[0]);
                    A[3] = sigmoid_f(q1v + bias2[1]);
                    *(float4v*)&xch[u * XCHS + xofs] = A;
                }
            } else {
                if (s == 1 && c + 1 < NCH) {
                    zx_burst(0, nb);
                } else if (s == 3 && c + 2 < NCH) {
                    const size_t cofs = (size_t)(c + 2) * (CH * INw);
#pragma unroll
                    for (int it = 0; it < 3; ++it)
                        if (st_ok[it]) xhold[it] = x[st_gof[it] + cofs];
                }
            }
            __syncthreads();   // B1: exchange published
            // ======== PHASE 2: update (IF) / staging write + zx (P) ========
            if (isIF) {
                const float4v A = *(const float4v*)&xch[u * XCHS + xofs];
                const float c0a = hi2 ? C0[2] : C0[0];
                const float c1a = hi2 ? C1[2] : C1[0];
                const float c0b = hi2 ? C0[3] : C0[1];
                const float c1b = hi2 ? C1[3] : C1[1];
                const float iv0 = sigmoid_f(c0a + bias2[0]);
                const float fv0 = sigmoid_f(c1a + bias2[1]);
                cst2[0] = fmaf(fv0, cst2[0], iv0 * A[0]);
                hnew2[0] = A[1] * tanh_f(cst2[0]);
                const float iv1 = sigmoid_f(c0b + bias2[0]);
                const float fv1 = sigmoid_f(c1b + bias2[1]);
                cst2[1] = fmaf(fv1, cst2[1], iv1 * A[2]);
                hnew2[1] = A[3] * tanh_f(cst2[1]);
                short* hwh = &h_hi[t & 1][0][0] + row0 * XS + u;
                short* hwl = &h_lo[t & 1][0][0] + row0 * XS + u;
                const unsigned short h0h = f2bf(hnew2[0]);
                hwh[0]  = (short)h0h;
                hwl[0]  = (short)f2bf(hnew2[0] - bf2f(h0h));
                const unsigned short h1h = f2bf(hnew2[1]);
                hwh[XS] = (short)h1h;
                hwl[XS] = (short)f2bf(hnew2[1] - bf2f(h1h));
            } else if (isP) {
                if (s == 0 && c + 1 < NCH) {
#pragma unroll
                    for (int it = 0; it < 3; ++it) {
                        if (st_ok[it]) {
                            const unsigned short hh = f2bf(xhold[it]);
                            xsh[st_lds[it]] = (short)hh;
                            xsl[st_lds[it]] = (short)f2bf(xhold[it] - bf2f(hh));
                        }
                    }
                } else if (s == 2 && c + 1 < NCH) {
                    zx_burst(1, nb);
                }
            }
            __syncthreads();   // B2: h + x published
        }
    }

    if (isIF) {
        hf_out[(size_t)(b0 + row0)     * HH + u] = hnew2[0];
        hf_out[(size_t)(b0 + row0 + 1) * HH + u] = hnew2[1];
    }
}

// ---------------------------------------------------------------------------
// Epilogue: backward dir = ONE LSTM step on x[:,T-1,:] (h0=c0=0, Whh_b unused),
// then FC + softmax.
// ---------------------------------------------------------------------------
__global__ __launch_bounds__(256) void lstm_bwd_fc(
    const float* __restrict__ x,
    const float* __restrict__ Wih,
    const float* __restrict__ bih,
    const float* __restrict__ bhh,
    const float* __restrict__ fcW,
    const float* __restrict__ fcb,
    const float* __restrict__ hf,
    float* __restrict__ out)
{
    __shared__ float xl[B2][48];
    __shared__ float act[B2][256];
    __shared__ float hbl[B2][HH];

    const int j  = threadIdx.x;
    const int b0 = blockIdx.x * B2;

    for (int e = j; e < B2 * INw; e += 256) {
        int b = e / INw, i = e - b * INw;
        xl[b][i] = x[((size_t)(b0 + b) * TT + (TT - 1)) * INw + i];
    }
    if (j < B2) { xl[j][46] = 0.f; xl[j][47] = 0.f; }
    __syncthreads();

    float4 wih4[12];
#pragma unroll
    for (int ii = 0; ii < 11; ++ii)
        wih4[ii] = make_float4(Wih[j*INw + 4*ii + 0], Wih[j*INw + 4*ii + 1],
                               Wih[j*INw + 4*ii + 2], Wih[j*INw + 4*ii + 3]);
    wih4[11] = make_float4(Wih[j*INw + 44], Wih[j*INw + 45], 0.f, 0.f);
    const float bias = bih[j] + bhh[j];
    const bool  gate_is_tanh = ((j >> 6) == 2);

#pragma unroll
    for (int b = 0; b < B2; ++b) {
        float a = bias;
#pragma unroll
        for (int ii = 0; ii < 12; ++ii) {
            float4 xv = *(const float4*)&xl[b][4*ii];
            a = dot4(wih4[ii], xv, a);
        }
        act[b][j] = gate_is_tanh ? tanh_f(a) : sigmoid_f(a);
    }
    __syncthreads();

    for (int q = j; q < B2 * HH; q += 256) {
        int b = q >> 6, ll = q & 63;
        float ig = act[b][ll];
        float gg = act[b][128 + ll];
        float og = act[b][192 + ll];
        hbl[b][ll] = og * tanh_f(ig * gg);
    }
    __syncthreads();

    if (j < B2 * NCLS) {
        int b = j >> 3, n = j & 7;
        float a = fcb[n];
        const float* hfr = hf + (size_t)(b0 + b) * HH;
#pragma unroll
        for (int ll = 0; ll < HH; ++ll) {
            a = fmaf(fcW[n * 2 * HH + ll],      hfr[ll],    a);
            a = fmaf(fcW[n * 2 * HH + HH + ll], hbl[b][ll], a);
        }
        float m = a;
        m = fmaxf(m, __shfl_xor(m, 1, 8));
        m = fmaxf(m, __shfl_xor(m, 2, 8));
        m = fmaxf(m, __shfl_xor(m, 4, 8));
        float e = __expf(a - m);
        float s = e;
        s += __shfl_xor(s, 1, 8);
        s += __shfl_xor(s, 2, 8);
        s += __shfl_xor(s, 4, 8);
        out[(size_t)(b0 + b) * NCLS + n] = e / s;
    }
}

extern "C" void kernel_launch(void* const* d_in, const int* in_sizes, int n_in,
                              void* d_out, int out_size, void* d_ws, size_t ws_size,
                              hipStream_t stream) {
    const float* x     = (const float*)d_in[0];
    const float* Wih_f = (const float*)d_in[1];
    const float* Whh_f = (const float*)d_in[2];
    const float* bih_f = (const float*)d_in[3];
    const float* bhh_f = (const float*)d_in[4];
    const float* Wih_b = (const float*)d_in[5];
    // d_in[6] = Whh_b: unused — backward dir contributes only its first step (h0=0)
    const float* bih_b = (const float*)d_in[7];
    const float* bhh_b = (const float*)d_in[8];
    const float* fcW   = (const float*)d_in[9];
    const float* fcb   = (const float*)d_in[10];
    float* out = (float*)d_out;
    float* hf  = (float*)d_ws;   // 2048*64 fp32 = 512 KB scratch

    hipLaunchKernelGGL(lstm_fwd_mfma, dim3(2048 / BB), dim3(1024), 0, stream,
                       x, Wih_f, Whh_f, bih_f, bhh_f, hf);
    hipLaunchKernelGGL(lstm_bwd_fc, dim3(2048 / B2), dim3(256), 0, stream,
                       x, Wih_b, bih_b, bhh_b, fcW, fcb, hf, out);
}